// Round 4
// baseline (270.785 us; speedup 1.0000x reference)
//
#include <hip/hip_runtime.h>

// ---------------------------------------------------------------------------
// SelfAttention: out = softmax((x@Wk+bk) @ (x@Wq+bq)^T) @ (x@Wv+bv)
// B=4, N=2048, E=A=1024, fp32 in/out.
// R12: T3-minimal double-buffer schedule on the R11 gemm (which measured
// proj 65us / MfmaUtil 36% = m97-structure ceiling). Delta vs R11:
//  - LDS 2x(TM+128)x64 (64KB, 2 blocks/CU); STAGE(t+1) issued BEFORE the
//    ds_read+MFMA of tile t; single vmcnt(0) AFTER MFMA; ONE raw s_barrier
//    per K-tile (was: barrier + drain-before-compute + barrier).
//    Loads for t+1 are in flight under ~300-400cy of tile-t compute.
//  - hoisted LDS swizzle offsets (identical addresses: r&7 == l15&7).
//  - XCD remap + TM=128 + grids unchanged from R11.
//  - accumulation order unchanged -> absmax bit-identical (0.08105469).
// Race-freedom: every wave's frag ds_reads are register-consumed before its
// barrier arrival (compiler dep-waits before last MFMA); vmcnt(0) before the
// barrier drains this wave's stage loads; after the barrier all waves'
// stages have landed and the just-read buffer may be overwritten next iter.
// ---------------------------------------------------------------------------

typedef __attribute__((ext_vector_type(8))) _Float16 half8;   // 4 VGPRs
typedef __attribute__((ext_vector_type(4))) float floatx4;

#define BK 64
#define MFMA16 __builtin_amdgcn_mfma_f32_16x16x32_f16
#define BARRIER() asm volatile("s_barrier" ::: "memory")
#define WAITV0()  asm volatile("s_waitcnt vmcnt(0)" ::: "memory")

static __device__ __forceinline__ unsigned short f2h(float f) {
    _Float16 h = (_Float16)f;          // RNE
    return *(unsigned short*)&h;
}

// async global->LDS, 16B per lane; LDS dst = wave-uniform base + lane*16
static __device__ __forceinline__ void gll16(const unsigned short* g,
                                             unsigned short* l) {
    __builtin_amdgcn_global_load_lds(
        (__attribute__((address_space(1))) void*)(g),
        (__attribute__((address_space(3))) void*)(l), 16, 0, 0);
}

// XCD-chunked bijective remap (m157; requires nwg % 8 == 0 — grids here are
// 1536 / 1024 / 512). [R10/R11: FETCH -22% on proj]
static __device__ __forceinline__ void xcd_remap(int& bx, int& by, int& bz) {
    const int gx = gridDim.x, gy = gridDim.y, gz = gridDim.z;
    const int flat = blockIdx.x + gx * (blockIdx.y + gy * blockIdx.z);
    const int w = (flat & 7) * ((gx * gy * gz) >> 3) + (flat >> 3);
    bx = w % gx;
    const int r = w / gx;
    by = r % gy;
    bz = r / gy;
}

// ---------------------------------------------------------------------------
// prep: blocks 0..8191 cast x -> fp16; 8192..11263 transpose W0..2 -> fp16;
// 11264..11275 bias concat.
// ---------------------------------------------------------------------------
__global__ __launch_bounds__(256)
void prep(const float* __restrict__ x,
          const float* __restrict__ W0, const float* __restrict__ W1,
          const float* __restrict__ W2,
          const float* __restrict__ b0, const float* __restrict__ b1,
          const float* __restrict__ b2,
          unsigned short* __restrict__ x16, unsigned short* __restrict__ WT,
          float* __restrict__ bias3) {
    __shared__ float tile[32][33];
    const int bid = blockIdx.x;
    if (bid < 8192) {
        int i = bid * 1024 + threadIdx.x * 4;
        float4 f = *(const float4*)(x + i);
        *(ushort4*)(x16 + i) =
            make_ushort4(f2h(f.x), f2h(f.y), f2h(f.z), f2h(f.w));
    } else if (bid < 11264) {
        int wz = bid - 8192;
        int z = wz >> 10;
        int t = wz & 1023;
        const float* W = z == 0 ? W0 : (z == 1 ? W1 : W2);
        unsigned short* Tz = WT + (size_t)z * 1024 * 1024;
        int c0 = (t & 31) * 32, r0 = (t >> 5) * 32;
        int tx = threadIdx.x & 31, ty = threadIdx.x >> 5;
#pragma unroll
        for (int j = 0; j < 32; j += 8)
            tile[ty + j][tx] = W[(r0 + ty + j) * 1024 + c0 + tx];
        __syncthreads();
#pragma unroll
        for (int j = 0; j < 32; j += 8)
            Tz[(c0 + ty + j) * 1024 + r0 + tx] = f2h(tile[tx][ty + j]);
    } else {
        int i = (bid - 11264) * 256 + threadIdx.x;
        int s = i >> 10;
        const float* b = s == 0 ? b0 : (s == 1 ? b1 : b2);
        bias3[i] = b[i & 1023];
    }
}

// ---------------------------------------------------------------------------
// NT GEMM, double-buffered (T3-minimal): C[M,N] = A[M,K]*B[N,K]^T (+bias).
// Block TM x 128, 256 threads (4 waves 2x2; wave tile TM/2 x 64), BK=64.
// Per tile: STAGE(t+1 -> buf^1) || ds_read+MFMA(buf) ; vmcnt(0); s_barrier.
// LDS: unpadded [row][64]; XOR chunk swizzle (pos p of row r holds chunk
// p ^ (r&7)) — conflict-free (rocprof 0 across R8-R11).
// mode 0: fp32 -> Cf; mode 2: fp16 segmented -> Ch (k|q|v contiguous).
// ---------------------------------------------------------------------------
template <int TM>
__global__ __launch_bounds__(256, 2)
void gemm_db(const unsigned short* __restrict__ A,
             const unsigned short* __restrict__ B,
             const float* __restrict__ bias,
             float* __restrict__ Cf,
             unsigned short* __restrict__ Ch,
             int mode, int M, int N, int K,
             long long sA, long long sB, long long sC) {
    constexpr int WM = TM / 2;       // wave tile rows
    constexpr int MI = WM / 16;      // acc row-tiles per wave
    __shared__ unsigned short smem[2][(TM + 128) * BK];

    const int tid = threadIdx.x;
    const int lane = tid & 63;
    const int wave = tid >> 6;          // 0..3
    const int quad = lane >> 4;
    const int l15 = lane & 15;
    const int wm = (wave & 1) * WM;
    const int wn = (wave >> 1) * 64;
    // hoisted swizzle offsets: every fragment row r has r&7 == l15&7
    const int poff0 = ((quad ^ (l15 & 7)) << 3);        // t=0, in shorts
    const int poff1 = (((4 + quad) ^ (l15 & 7)) << 3);  // t=1

    int bx, by, bz;
    xcd_remap(bx, by, bz);
    const long long zA = (long long)bz * sA;
    const long long zB = (long long)bz * sB;
    const long long zC = (long long)bz * sC;
    const int m0 = by * TM;
    const int n0 = bx * 128;

    // staging: lane i covers row i>>3; position p=i&7 gets chunk p ^ (row&7)
    const int arow = wave * (TM / 4) + (lane >> 3);
    const int brow = wave * 32 + (lane >> 3);
    const int schunk8 = (((lane & 7) ^ ((lane >> 3) & 7)) << 3);
    const long long aoff = zA + (long long)(m0 + arow) * K + schunk8;
    const long long boff = zB + (long long)(n0 + brow) * K + schunk8;

#define STAGE(b, k0)                                                         \
    {                                                                        \
        _Pragma("unroll") for (int j = 0; j < TM / 32; ++j)                  \
            gll16(A + aoff + (k0) + (long long)j * 8 * K,                    \
                  &smem[b][(wave * (TM / 4) + j * 8) * BK]);                 \
        _Pragma("unroll") for (int j = 0; j < 4; ++j)                        \
            gll16(B + boff + (k0) + (long long)j * 8 * K,                    \
                  &smem[b][(TM + wave * 32 + j * 8) * BK]);                  \
    }

    floatx4 zero = {0.f, 0.f, 0.f, 0.f};
    floatx4 acc[MI][4];
#pragma unroll
    for (int i = 0; i < MI; ++i)
#pragma unroll
        for (int j = 0; j < 4; ++j) acc[i][j] = zero;

    // prologue: fill buffer 0
    STAGE(0, 0);
    WAITV0();
    BARRIER();

    int cur = 0;
    for (int k0 = 0; k0 < K; k0 += BK, cur ^= 1) {
        // 1) issue next tile's stage into the idle buffer (flies under MFMA)
        if (k0 + BK < K) STAGE(cur ^ 1, k0 + BK);

        // 2) compute current buffer
        const unsigned short* As = smem[cur];
        const unsigned short* Bs = smem[cur] + (size_t)TM * BK;
        half8 a0[MI], b0[4], a1[MI], b1[4];
#pragma unroll
        for (int mi = 0; mi < MI; ++mi)
            a0[mi] = *(const half8*)&As[(wm + mi * 16 + l15) * BK + poff0];
#pragma unroll
        for (int ni = 0; ni < 4; ++ni)
            b0[ni] = *(const half8*)&Bs[(wn + ni * 16 + l15) * BK + poff0];
#pragma unroll
        for (int mi = 0; mi < MI; ++mi)
#pragma unroll
            for (int ni = 0; ni < 4; ++ni)
                acc[mi][ni] = MFMA16(a0[mi], b0[ni], acc[mi][ni], 0, 0, 0);
#pragma unroll
        for (int mi = 0; mi < MI; ++mi)
            a1[mi] = *(const half8*)&As[(wm + mi * 16 + l15) * BK + poff1];
#pragma unroll
        for (int ni = 0; ni < 4; ++ni)
            b1[ni] = *(const half8*)&Bs[(wn + ni * 16 + l15) * BK + poff1];
#pragma unroll
        for (int mi = 0; mi < MI; ++mi)
#pragma unroll
            for (int ni = 0; ni < 4; ++ni)
                acc[mi][ni] = MFMA16(a1[mi], b1[ni], acc[mi][ni], 0, 0, 0);

        // 3) drain own stage loads; one barrier per tile
        WAITV0();
        BARRIER();
    }
#undef STAGE

    // epilogue: C/D layout col=lane&15, row=quad*4+reg  [verified m89/m91]
#pragma unroll
    for (int mi = 0; mi < MI; ++mi)
#pragma unroll
        for (int ni = 0; ni < 4; ++ni) {
            int colg = n0 + wn + ni * 16 + l15;
            float bv = bias ? bias[colg] : 0.f;
#pragma unroll
            for (int r = 0; r < 4; ++r) {
                int rowg = m0 + wm + mi * 16 + quad * 4 + r;
                float v = acc[mi][ni][r] + bv;
                if (mode == 0) {
                    Cf[zC + (long long)rowg * N + colg] = v;
                } else {  // mode 2: segmented fp16 (k16|q16|v16 contiguous)
                    int seg = colg >> 10;
                    Ch[(long long)seg * sC + (long long)rowg * 1024 +
                       (colg & 1023)] = f2h(v);
                }
            }
        }
}

// ---------------------------------------------------------------------------
// fused: blocks 0..8191 = row softmax (scores fp32 [8192][2048] -> attn fp16)
//        blocks 8192..16383 = v16 [z][2048][1024] -> vT [z][1024][2048]
// ---------------------------------------------------------------------------
__global__ __launch_bounds__(256)
void softmax_vT(const float* __restrict__ S, unsigned short* __restrict__ P,
                const unsigned short* __restrict__ v,
                unsigned short* __restrict__ vT) {
    __shared__ float red_m[4];
    __shared__ float red_s[4];
    __shared__ unsigned short tile[32][33];
    const int bid = blockIdx.x;
    const int tid = threadIdx.x;

    if (bid < 8192) {
        const float* s = S + (long long)bid * 2048;
        unsigned short* p = P + (long long)bid * 2048;
        const int lane = tid & 63;
        const int wave = tid >> 6;

        float4 v0 = *(const float4*)(s + tid * 8);
        float4 v1 = *(const float4*)(s + tid * 8 + 4);
        float vals[8] = {v0.x, v0.y, v0.z, v0.w, v1.x, v1.y, v1.z, v1.w};

        float m = vals[0];
#pragma unroll
        for (int i = 1; i < 8; ++i) m = fmaxf(m, vals[i]);
#pragma unroll
        for (int off = 32; off >= 1; off >>= 1)
            m = fmaxf(m, __shfl_xor(m, off));
        if (lane == 0) red_m[wave] = m;
        __syncthreads();
        m = fmaxf(fmaxf(red_m[0], red_m[1]), fmaxf(red_m[2], red_m[3]));

        float e[8];
        float sum = 0.f;
#pragma unroll
        for (int i = 0; i < 8; ++i) {
            e[i] = __expf(vals[i] - m);
            sum += e[i];
        }
#pragma unroll
        for (int off = 32; off >= 1; off >>= 1) sum += __shfl_xor(sum, off);
        if (lane == 0) red_s[wave] = sum;
        __syncthreads();
        sum = red_s[0] + red_s[1] + red_s[2] + red_s[3];
        float inv = 1.0f / sum;

        unsigned short ob[8];
#pragma unroll
        for (int i = 0; i < 8; ++i) ob[i] = f2h(e[i] * inv);
        *(ushort4*)(p + tid * 8)     = make_ushort4(ob[0], ob[1], ob[2], ob[3]);
        *(ushort4*)(p + tid * 8 + 4) = make_ushort4(ob[4], ob[5], ob[6], ob[7]);
    } else {
        int t = bid - 8192;
        int z = t >> 11;                 // batch
        int rest = t & 2047;             // 32 col-tiles x 64 row-tiles
        int c0 = (rest & 31) * 32;
        int r0 = (rest >> 5) * 32;
        long long zs = (long long)z * 2048 * 1024;
        int tx = tid & 31, ty = tid >> 5;
#pragma unroll
        for (int j = 0; j < 32; j += 8)
            tile[ty + j][tx] = v[zs + (long long)(r0 + ty + j) * 1024 + c0 + tx];
        __syncthreads();
#pragma unroll
        for (int j = 0; j < 32; j += 8)
            vT[zs + (long long)(c0 + ty + j) * 2048 + r0 + tx] =
                tile[tx][ty + j];
    }
}

// ---------------------------------------------------------------------------
extern "C" void kernel_launch(void* const* d_in, const int* in_sizes, int n_in,
                              void* d_out, int out_size, void* d_ws,
                              size_t ws_size, hipStream_t stream) {
    const float* x  = (const float*)d_in[0];
    const float* Wk = (const float*)d_in[1];
    const float* bk = (const float*)d_in[2];
    const float* Wq = (const float*)d_in[3];
    const float* bq = (const float*)d_in[4];
    const float* Wv = (const float*)d_in[5];
    const float* bv = (const float*)d_in[6];
    float* out = (float*)d_out;

    const int Bb = 4, Ns = 2048, E = 1024, Aa = 1024;
    const int M = Bb * Ns;  // 8192

    char* p = (char*)d_ws;
    auto alloc = [&](size_t bytes) {
        char* r = p;
        p += (bytes + 255) & ~(size_t)255;
        return r;
    };
    const size_t MA = (size_t)M * Aa;          // 8.39M elems
    unsigned short* x16 = (unsigned short*)alloc(MA * 2);
    unsigned short* WT  = (unsigned short*)alloc((size_t)3 * E * Aa * 2);
    // k16,q16,v16 MUST be contiguous (segmented epilogue): MA*2 is a
    // multiple of 256, so alloc() inserts no padding.
    unsigned short* k16 = (unsigned short*)alloc(MA * 2);
    unsigned short* q16 = (unsigned short*)alloc(MA * 2);
    unsigned short* v16 = (unsigned short*)alloc(MA * 2);
    unsigned short* vT  = (unsigned short*)alloc(MA * 2);
    unsigned short* attn = (unsigned short*)alloc((size_t)M * Ns * 2);
    float* bias3 = (float*)alloc(3072 * 4);
    float* scores = (float*)alloc((size_t)Bb * Ns * Ns * 4);

    // 1. prep: x->fp16, W^T x3, bias concat (one dispatch)
    prep<<<11276, 256, 0, stream>>>(x, Wk, Wq, Wv, bk, bq, bv, x16, WT, bias3);

    // 2. fused projections: [k|q|v] = x16 @ [Wk|Wq|Wv]^T + bias3
    //    grid 24 x 64 = 1536 blocks
    gemm_db<128><<<dim3(3 * Aa / 128, M / 128, 1), 256, 0, stream>>>(
        x16, WT, bias3, nullptr, k16, 2, M, 3 * Aa, E, 0, 0, (long long)MA);

    // 3. scores[b,n,m] = k[b,n,:] . q[b,m,:]   grid 16 x 16 x 4 = 1024
    gemm_db<128><<<dim3(Ns / 128, Ns / 128, Bb), 256, 0, stream>>>(
        k16, q16, nullptr, scores, nullptr, 0, Ns, Ns, Aa,
        (long long)Ns * Aa, (long long)Ns * Aa, (long long)Ns * Ns);

    // 4. softmax rows -> fp16 attn; v -> v^T (one dispatch)
    softmax_vT<<<16384, 256, 0, stream>>>(scores, attn, v16, vT);

    // 5. out[b,n,a] = sum_m attn[b,n,m] * vT[b,a,m]   grid 512 blocks
    gemm_db<128><<<dim3(Aa / 128, Ns / 128, Bb), 256, 0, stream>>>(
        attn, vT, nullptr, out, nullptr, 0, Ns, Aa, Ns,
        (long long)Ns * Ns, (long long)Aa * Ns, (long long)Ns * Aa);
}

// Round 5
// 256.481 us; speedup vs baseline: 1.0558x; 1.0558x over previous
//
#include <hip/hip_runtime.h>

// ---------------------------------------------------------------------------
// SelfAttention: out = softmax((x@Wk+bk) @ (x@Wq+bq)^T) @ (x@Wv+bv)
// B=4, N=2048, E=A=1024, fp32 in/out.
// R13: base = R11 (best, 266.9us; R12 dbuf regressed via occupancy loss).
//  - PV: TN=64 (block 128x64, 24KB LDS) -> grid 1024, residency 2->4/CU.
//  - v->vT transpose hoisted into the scores dispatch (needs only v16):
//    split-remap gives each XCD 128 XCD-chunked scores blocks first +
//    1024 transpose tiles that backfill bubbles/tail. softmax dispatch is
//    now pure softmax (8192 blocks).
//  - per-output arithmetic unchanged -> absmax bit-identical (0.08105469).
// ---------------------------------------------------------------------------

typedef __attribute__((ext_vector_type(8))) _Float16 half8;   // 4 VGPRs
typedef __attribute__((ext_vector_type(4))) float floatx4;

#define BK 64
#define MFMA16 __builtin_amdgcn_mfma_f32_16x16x32_f16

static __device__ __forceinline__ unsigned short f2h(float f) {
    _Float16 h = (_Float16)f;          // RNE
    return *(unsigned short*)&h;
}

// async global->LDS, 16B per lane; LDS dst = wave-uniform base + lane*16
static __device__ __forceinline__ void gll16(const unsigned short* g,
                                             unsigned short* l) {
    __builtin_amdgcn_global_load_lds(
        (__attribute__((address_space(1))) void*)(g),
        (__attribute__((address_space(3))) void*)(l), 16, 0, 0);
}

// XCD-chunked bijective remap (m157; requires nwg % 8 == 0).
static __device__ __forceinline__ void xcd_remap(int& bx, int& by, int& bz) {
    const int gx = gridDim.x, gy = gridDim.y, gz = gridDim.z;
    const int flat = blockIdx.x + gx * (blockIdx.y + gy * blockIdx.z);
    const int w = (flat & 7) * ((gx * gy * gz) >> 3) + (flat >> 3);
    bx = w % gx;
    const int r = w / gx;
    by = r % gy;
    bz = r / gy;
}

// ---------------------------------------------------------------------------
// prep: blocks 0..8191 cast x -> fp16; 8192..11263 transpose W0..2 -> fp16;
// 11264..11275 bias concat.
// ---------------------------------------------------------------------------
__global__ __launch_bounds__(256)
void prep(const float* __restrict__ x,
          const float* __restrict__ W0, const float* __restrict__ W1,
          const float* __restrict__ W2,
          const float* __restrict__ b0, const float* __restrict__ b1,
          const float* __restrict__ b2,
          unsigned short* __restrict__ x16, unsigned short* __restrict__ WT,
          float* __restrict__ bias3) {
    __shared__ float tile[32][33];
    const int bid = blockIdx.x;
    if (bid < 8192) {
        int i = bid * 1024 + threadIdx.x * 4;
        float4 f = *(const float4*)(x + i);
        *(ushort4*)(x16 + i) =
            make_ushort4(f2h(f.x), f2h(f.y), f2h(f.z), f2h(f.w));
    } else if (bid < 11264) {
        int wz = bid - 8192;
        int z = wz >> 10;
        int t = wz & 1023;
        const float* W = z == 0 ? W0 : (z == 1 ? W1 : W2);
        unsigned short* Tz = WT + (size_t)z * 1024 * 1024;
        int c0 = (t & 31) * 32, r0 = (t >> 5) * 32;
        int tx = threadIdx.x & 31, ty = threadIdx.x >> 5;
#pragma unroll
        for (int j = 0; j < 32; j += 8)
            tile[ty + j][tx] = W[(r0 + ty + j) * 1024 + c0 + tx];
        __syncthreads();
#pragma unroll
        for (int j = 0; j < 32; j += 8)
            Tz[(c0 + ty + j) * 1024 + r0 + tx] = f2h(tile[tx][ty + j]);
    } else {
        int i = (bid - 11264) * 256 + threadIdx.x;
        int s = i >> 10;
        const float* b = s == 0 ? b0 : (s == 1 ? b1 : b2);
        bias3[i] = b[i & 1023];
    }
}

// ---------------------------------------------------------------------------
// NT GEMM body (R11 structure, 2-barrier single-buffer, verified 36% Mfma):
// C[M,N] = A[M,K]*B[N,K]^T (+bias[col]); fp16 in, fp32 acc.
// Block TM x TN, 256 threads (4 waves 2x2; wave tile TM/2 x TN/2), BK=64.
// LDS: unpadded [row][64]; XOR chunk swizzle (pos p of row r holds chunk
// p ^ (r&7)) — conflict-free (rocprof 0 across R8-R12).
// mode 0: fp32 -> Cf; mode 2: fp16 segmented -> Ch (k|q|v contiguous).
// ---------------------------------------------------------------------------
template <int TM, int TN>
static __device__ __forceinline__ void gemm_body(
    unsigned short* smem, int bx, int by, int bz,
    const unsigned short* __restrict__ A,
    const unsigned short* __restrict__ B,
    const float* __restrict__ bias,
    float* __restrict__ Cf, unsigned short* __restrict__ Ch,
    int mode, int N, int K, long long sA, long long sB, long long sC) {
    constexpr int WM = TM / 2;       // wave tile rows
    constexpr int MI = WM / 16;      // acc row-tiles per wave
    constexpr int WN = TN / 2;
    constexpr int NI = WN / 16;      // acc col-tiles per wave
    unsigned short* As = smem;                  // TM x BK
    unsigned short* Bs = smem + TM * BK;        // TN x BK

    const int tid = threadIdx.x;
    const int lane = tid & 63;
    const int wave = tid >> 6;          // 0..3
    const int quad = lane >> 4;
    const int l15 = lane & 15;
    const int wm = (wave & 1) * WM;
    const int wn = (wave >> 1) * WN;

    const long long zA = (long long)bz * sA;
    const long long zB = (long long)bz * sB;
    const long long zC = (long long)bz * sC;
    const int m0 = by * TM;
    const int n0 = bx * TN;

    // staging: lane i covers row i>>3; position p=i&7 gets chunk p ^ (row&7)
    const int arow = wave * (TM / 4) + (lane >> 3);
    const int brow = wave * (TN / 4) + (lane >> 3);
    const int schunk8 = (((lane & 7) ^ ((lane >> 3) & 7)) << 3);
    const long long aoff = zA + (long long)(m0 + arow) * K + schunk8;
    const long long boff = zB + (long long)(n0 + brow) * K + schunk8;
    unsigned short* lA = As + (wave * (TM / 4)) * BK;
    unsigned short* lB = Bs + (wave * (TN / 4)) * BK;

    floatx4 zero = {0.f, 0.f, 0.f, 0.f};
    floatx4 acc[MI][NI];
#pragma unroll
    for (int i = 0; i < MI; ++i)
#pragma unroll
        for (int j = 0; j < NI; ++j) acc[i][j] = zero;

    for (int k0 = 0; k0 < K; k0 += BK) {
        __syncthreads();
#pragma unroll
        for (int j = 0; j < TM / 32; ++j)
            gll16(A + aoff + k0 + (long long)j * 8 * K, lA + j * 8 * BK);
#pragma unroll
        for (int j = 0; j < TN / 32; ++j)
            gll16(B + boff + k0 + (long long)j * 8 * K, lB + j * 8 * BK);
        __syncthreads();

#pragma unroll
        for (int t = 0; t < 2; ++t) {      // two K=32 MFMA steps per BK=64
            half8 a[MI], b[NI];
#pragma unroll
            for (int mi = 0; mi < MI; ++mi) {
                int r = wm + mi * 16 + l15;
                int p = (t * 4 + quad) ^ (r & 7);
                a[mi] = *(const half8*)&As[r * BK + p * 8];
            }
#pragma unroll
            for (int ni = 0; ni < NI; ++ni) {
                int r = wn + ni * 16 + l15;
                int p = (t * 4 + quad) ^ (r & 7);
                b[ni] = *(const half8*)&Bs[r * BK + p * 8];
            }
#pragma unroll
            for (int mi = 0; mi < MI; ++mi)
#pragma unroll
                for (int ni = 0; ni < NI; ++ni)
                    acc[mi][ni] = MFMA16(a[mi], b[ni], acc[mi][ni], 0, 0, 0);
        }
    }

    // epilogue: C/D layout col=lane&15, row=quad*4+reg  [verified m89/m91]
#pragma unroll
    for (int mi = 0; mi < MI; ++mi)
#pragma unroll
        for (int ni = 0; ni < NI; ++ni) {
            int colg = n0 + wn + ni * 16 + l15;
            float bv = bias ? bias[colg] : 0.f;
#pragma unroll
            for (int r = 0; r < 4; ++r) {
                int rowg = m0 + wm + mi * 16 + quad * 4 + r;
                float v = acc[mi][ni][r] + bv;
                if (mode == 0) {
                    Cf[zC + (long long)rowg * N + colg] = v;
                } else {  // mode 2: segmented fp16 (k16|q16|v16 contiguous)
                    int seg = colg >> 10;
                    Ch[(long long)seg * sC + (long long)rowg * 1024 +
                       (colg & 1023)] = f2h(v);
                }
            }
        }
}

// plain GEMM kernel (proj, PV): m157 XCD remap + body
template <int TM, int TN>
__global__ __launch_bounds__(256, 2)
void gemm_nt(const unsigned short* __restrict__ A,
             const unsigned short* __restrict__ B,
             const float* __restrict__ bias,
             float* __restrict__ Cf,
             unsigned short* __restrict__ Ch,
             int mode, int N, int K,
             long long sA, long long sB, long long sC) {
    __shared__ unsigned short smem[(TM + TN) * BK];
    int bx, by, bz;
    xcd_remap(bx, by, bz);
    gemm_body<TM, TN>(smem, bx, by, bz, A, B, bias, Cf, Ch, mode, N, K,
                      sA, sB, sC);
}

// ---------------------------------------------------------------------------
// scores + vT dispatch: 9216 blocks. Physical block f -> XCD c = f&7,
// rank = f>>3. rank<128: scores GEMM block (XCD-chunked: w = c*128+rank over
// the (16,16,4) scores grid — 128 contiguous work ids per XCD = R11-style L2
// chunking; these launch first and stay resident). rank>=128: one 32x32
// v16->vT transpose tile (backfills the 5th LDS slot + scores' tail; its
// 67MB of traffic rides in scores' idle BW).
// ---------------------------------------------------------------------------
__global__ __launch_bounds__(256, 2)
void scores_vT(const unsigned short* __restrict__ k16,
               const unsigned short* __restrict__ q16,
               float* __restrict__ S,
               const unsigned short* __restrict__ v,
               unsigned short* __restrict__ vT) {
    __shared__ unsigned short smem[(128 + 128) * BK];
    const int f = blockIdx.x;
    const int c = f & 7;
    const int rank = f >> 3;
    if (rank < 128) {
        const int w = c * 128 + rank;          // scores work id, XCD-chunked
        const int bx = w & 15;
        const int by = (w >> 4) & 15;
        const int bz = w >> 8;
        gemm_body<128, 128>(smem, bx, by, bz, k16, q16, nullptr, S, nullptr,
                            0, 2048, 1024,
                            (long long)2048 * 1024, (long long)2048 * 1024,
                            (long long)2048 * 2048);
    } else {
        // transpose tile: t in [0,8192)
        const int t = c * 1024 + (rank - 128);
        auto tile = (unsigned short(*)[33])smem;   // 32x33 ushort = 2112 B
        const int tid = threadIdx.x;
        int z = t >> 11;                 // batch
        int rest = t & 2047;             // 32 col-tiles x 64 row-tiles
        int c0 = (rest & 31) * 32;
        int r0 = (rest >> 5) * 32;
        long long zs = (long long)z * 2048 * 1024;
        int tx = tid & 31, ty = tid >> 5;
#pragma unroll
        for (int j = 0; j < 32; j += 8)
            tile[ty + j][tx] = v[zs + (long long)(r0 + ty + j) * 1024 + c0 + tx];
        __syncthreads();
#pragma unroll
        for (int j = 0; j < 32; j += 8)
            vT[zs + (long long)(c0 + ty + j) * 2048 + r0 + tx] =
                tile[tx][ty + j];
    }
}

// ---------------------------------------------------------------------------
// row softmax: scores fp32 [8192][2048] -> attn fp16 (one block per row)
// ---------------------------------------------------------------------------
__global__ __launch_bounds__(256)
void softmax_rows(const float* __restrict__ S, unsigned short* __restrict__ P) {
    __shared__ float red_m[4];
    __shared__ float red_s[4];
    const int bid = blockIdx.x;
    const int tid = threadIdx.x;

    const float* s = S + (long long)bid * 2048;
    unsigned short* p = P + (long long)bid * 2048;
    const int lane = tid & 63;
    const int wave = tid >> 6;

    float4 v0 = *(const float4*)(s + tid * 8);
    float4 v1 = *(const float4*)(s + tid * 8 + 4);
    float vals[8] = {v0.x, v0.y, v0.z, v0.w, v1.x, v1.y, v1.z, v1.w};

    float m = vals[0];
#pragma unroll
    for (int i = 1; i < 8; ++i) m = fmaxf(m, vals[i]);
#pragma unroll
    for (int off = 32; off >= 1; off >>= 1)
        m = fmaxf(m, __shfl_xor(m, off));
    if (lane == 0) red_m[wave] = m;
    __syncthreads();
    m = fmaxf(fmaxf(red_m[0], red_m[1]), fmaxf(red_m[2], red_m[3]));

    float e[8];
    float sum = 0.f;
#pragma unroll
    for (int i = 0; i < 8; ++i) {
        e[i] = __expf(vals[i] - m);
        sum += e[i];
    }
#pragma unroll
    for (int off = 32; off >= 1; off >>= 1) sum += __shfl_xor(sum, off);
    if (lane == 0) red_s[wave] = sum;
    __syncthreads();
    sum = red_s[0] + red_s[1] + red_s[2] + red_s[3];
    float inv = 1.0f / sum;

    unsigned short ob[8];
#pragma unroll
    for (int i = 0; i < 8; ++i) ob[i] = f2h(e[i] * inv);
    *(ushort4*)(p + tid * 8)     = make_ushort4(ob[0], ob[1], ob[2], ob[3]);
    *(ushort4*)(p + tid * 8 + 4) = make_ushort4(ob[4], ob[5], ob[6], ob[7]);
}

// ---------------------------------------------------------------------------
extern "C" void kernel_launch(void* const* d_in, const int* in_sizes, int n_in,
                              void* d_out, int out_size, void* d_ws,
                              size_t ws_size, hipStream_t stream) {
    const float* x  = (const float*)d_in[0];
    const float* Wk = (const float*)d_in[1];
    const float* bk = (const float*)d_in[2];
    const float* Wq = (const float*)d_in[3];
    const float* bq = (const float*)d_in[4];
    const float* Wv = (const float*)d_in[5];
    const float* bv = (const float*)d_in[6];
    float* out = (float*)d_out;

    const int Bb = 4, Ns = 2048, E = 1024, Aa = 1024;
    const int M = Bb * Ns;  // 8192

    char* p = (char*)d_ws;
    auto alloc = [&](size_t bytes) {
        char* r = p;
        p += (bytes + 255) & ~(size_t)255;
        return r;
    };
    const size_t MA = (size_t)M * Aa;          // 8.39M elems
    unsigned short* x16 = (unsigned short*)alloc(MA * 2);
    unsigned short* WT  = (unsigned short*)alloc((size_t)3 * E * Aa * 2);
    // k16,q16,v16 MUST be contiguous (segmented epilogue): MA*2 is a
    // multiple of 256, so alloc() inserts no padding.
    unsigned short* k16 = (unsigned short*)alloc(MA * 2);
    unsigned short* q16 = (unsigned short*)alloc(MA * 2);
    unsigned short* v16 = (unsigned short*)alloc(MA * 2);
    unsigned short* vT  = (unsigned short*)alloc(MA * 2);
    unsigned short* attn = (unsigned short*)alloc((size_t)M * Ns * 2);
    float* bias3 = (float*)alloc(3072 * 4);
    float* scores = (float*)alloc((size_t)Bb * Ns * Ns * 4);

    // 1. prep: x->fp16, W^T x3, bias concat (one dispatch)
    prep<<<11276, 256, 0, stream>>>(x, Wk, Wq, Wv, bk, bq, bv, x16, WT, bias3);

    // 2. fused projections: [k|q|v] = x16 @ [Wk|Wq|Wv]^T + bias3
    //    grid 24 x 64 = 1536 blocks (~5/CU, at the residency knee)
    gemm_nt<128, 128><<<dim3(3 * Aa / 128, M / 128, 1), 256, 0, stream>>>(
        x16, WT, bias3, nullptr, k16, 2, 3 * Aa, E, 0, 0, (long long)MA);

    // 3. scores (1024 XCD-chunked GEMM blocks) + v->vT (8192 backfill tiles)
    scores_vT<<<9216, 256, 0, stream>>>(k16, q16, scores, v16, vT);

    // 4. softmax rows -> fp16 attn (pure, BW-bound)
    softmax_rows<<<8192, 256, 0, stream>>>(scores, attn);

    // 5. out[b,n,a] = sum_m attn[b,n,m] * vT[b,a,m]
    //    TN=64: grid 16x16x4 = 1024 blocks, residency 2->4/CU
    gemm_nt<128, 64><<<dim3(Aa / 64, Ns / 128, Bb), 256, 0, stream>>>(
        attn, vT, nullptr, out, nullptr, 0, Aa, Ns,
        (long long)Ns * Ns, (long long)Aa * Ns, (long long)Ns * Aa);
}